// Round 9
// baseline (220.878 us; speedup 1.0000x reference)
//
#include <hip/hip_runtime.h>

#define NN 50000
#define NE 800000
#define C 64
#define NL 4
#define SCAN_NB 196            // ceil(50000/256)
#define CSR_CAP 1150016        // NE + NN*7/2 upper bound, padded, mult of 16

// ---------------- init: deg_cnt=0, csr=NN (pad sentinel), dummy y rows = 0 ----------------
__global__ void init_kernel(int* __restrict__ deg_cnt, int* __restrict__ csr,
                            float* __restrict__ y0, float* __restrict__ y1) {
    int i = blockIdx.x * blockDim.x + threadIdx.x;
    int stride = gridDim.x * blockDim.x;
    int4* c4 = (int4*)csr;
    for (int j = i; j < CSR_CAP / 4; j += stride)
        c4[j] = make_int4(NN, NN, NN, NN);
    if (i < (NN + 16) / 4)
        ((int4*)deg_cnt)[i] = make_int4(0, 0, 0, 0);
    if (i < 16)
        ((float4*)(y0 + (size_t)NN * C))[i] = make_float4(0.f, 0.f, 0.f, 0.f);
    else if (i < 32)
        ((float4*)(y1 + (size_t)NN * C))[i - 16] = make_float4(0.f, 0.f, 0.f, 0.f);
}

// ---------------- histogram + rank: 4 edges/thread (4 independent atomic chains) ----------------
__global__ void hist_rank_kernel(const int* __restrict__ dst, int* __restrict__ deg_cnt,
                                 int* __restrict__ rank) {
    int t = blockIdx.x * blockDim.x + threadIdx.x;
    int e0 = t * 4;
    if (e0 + 3 < NE) {
        int4 d4 = ((const int4*)dst)[t];
        int4 r4;
        r4.x = atomicAdd(&deg_cnt[d4.x], 1);
        r4.y = atomicAdd(&deg_cnt[d4.y], 1);
        r4.z = atomicAdd(&deg_cnt[d4.z], 1);
        r4.w = atomicAdd(&deg_cnt[d4.w], 1);
        ((int4*)rank)[t] = r4;
    } else if (e0 < NE) {
        for (int e = e0; e < NE; e++)
            rank[e] = atomicAdd(&deg_cnt[dst[e]], 1);
    }
}

// ---------------- scan1: per-block exclusive scan over PADDED degrees ----------------
__global__ __launch_bounds__(256) void scan1_kernel(const int* __restrict__ deg_cnt,
                                                    int* __restrict__ row_start,
                                                    int* __restrict__ bsums) {
    __shared__ int sdata[256];
    int tid = threadIdx.x;
    int i = blockIdx.x * 256 + tid;
    int v = (i < NN) ? ((deg_cnt[i] + 7) & ~7) : 0;   // pad to mult of 8
    sdata[tid] = v;
    __syncthreads();
    for (int off = 1; off < 256; off <<= 1) {
        int t = (tid >= off) ? sdata[tid - off] : 0;
        __syncthreads();
        sdata[tid] += t;
        __syncthreads();
    }
    int incl = sdata[tid];
    if (i < NN) row_start[i] = incl - v;
    if (tid == 255) bsums[blockIdx.x] = incl;
}

// ---------------- scan23: redundant block-sum scan + apply + deg_inv ----------------
__global__ __launch_bounds__(256) void scan23_kernel(int* __restrict__ row_start,
                                                     const int* __restrict__ bsums,
                                                     const int* __restrict__ deg_cnt,
                                                     float* __restrict__ deg_inv) {
    __shared__ int sdata[256];
    int tid = threadIdx.x;
    int v = (tid < SCAN_NB) ? bsums[tid] : 0;
    sdata[tid] = v;
    __syncthreads();
    for (int off = 1; off < 256; off <<= 1) {
        int t = (tid >= off) ? sdata[tid - off] : 0;
        __syncthreads();
        sdata[tid] += t;
        __syncthreads();
    }
    int b = blockIdx.x;
    int offset = (b == 0) ? 0 : sdata[b - 1];
    int i = b * 256 + tid;
    if (i < NN) {
        row_start[i] += offset;
        deg_inv[i] = 1.0f / fmaxf((float)deg_cnt[i], 1.0f);
    }
}

// ---------------- CSR fill: no atomics, 4 edges/thread ----------------
__global__ void fill_kernel(const int* __restrict__ src, const int* __restrict__ dst,
                            const int* __restrict__ rank, const int* __restrict__ row_start,
                            int* __restrict__ csr_src) {
    int t = blockIdx.x * blockDim.x + threadIdx.x;
    int e0 = t * 4;
    if (e0 + 3 < NE) {
        int4 d4 = ((const int4*)dst)[t];
        int4 r4 = ((const int4*)rank)[t];
        int4 s4 = ((const int4*)src)[t];
        csr_src[row_start[d4.x] + r4.x] = s4.x;
        csr_src[row_start[d4.y] + r4.y] = s4.y;
        csr_src[row_start[d4.z] + r4.z] = s4.z;
        csr_src[row_start[d4.w] + r4.w] = s4.w;
    } else if (e0 < NE) {
        for (int e = e0; e < NE; e++)
            csr_src[row_start[dst[e]] + rank[e]] = src[e];
    }
}

// ---------------- gather core: padded rows (mult of 8), no masks, int4 index loads ----------------
__device__ __forceinline__ float4 gather_row(const float4* __restrict__ y4,
                                             const int* __restrict__ cp, int dpad, int ql) {
    float4 acc = make_float4(0.f, 0.f, 0.f, 0.f);
    for (int t = 0; t < dpad; t += 8) {
        int4 ia = ((const int4*)(cp + t))[0];
        int4 ib = ((const int4*)(cp + t))[1];
        float4 v0 = y4[(size_t)ia.x * 16 + ql];
        float4 v1 = y4[(size_t)ia.y * 16 + ql];
        float4 v2 = y4[(size_t)ia.z * 16 + ql];
        float4 v3 = y4[(size_t)ia.w * 16 + ql];
        float4 v4 = y4[(size_t)ib.x * 16 + ql];
        float4 v5 = y4[(size_t)ib.y * 16 + ql];
        float4 v6 = y4[(size_t)ib.z * 16 + ql];
        float4 v7 = y4[(size_t)ib.w * 16 + ql];
        acc.x += v0.x; acc.y += v0.y; acc.z += v0.z; acc.w += v0.w;
        acc.x += v1.x; acc.y += v1.y; acc.z += v1.z; acc.w += v1.w;
        acc.x += v2.x; acc.y += v2.y; acc.z += v2.z; acc.w += v2.w;
        acc.x += v3.x; acc.y += v3.y; acc.z += v3.z; acc.w += v3.w;
        acc.x += v4.x; acc.y += v4.y; acc.z += v4.z; acc.w += v4.w;
        acc.x += v5.x; acc.y += v5.y; acc.z += v5.z; acc.w += v5.w;
        acc.x += v6.x; acc.y += v6.y; acc.z += v6.z; acc.w += v6.w;
        acc.x += v7.x; acc.y += v7.y; acc.z += v7.z; acc.w += v7.w;
    }
    return acc;
}

// ---------------- K1: dense transform (layer 0); y has NN+1 rows (row NN = 0) ----------------
__global__ __launch_bounds__(512) void transform_kernel(
    const float* __restrict__ xin,
    const float* __restrict__ Wl, const float* __restrict__ Wr,
    const float* __restrict__ bias,
    float* __restrict__ y, float* __restrict__ z)
{
    __shared__ float wl[C * C];
    __shared__ float wr[C * C];
    __shared__ float xs[64][C + 4];

    int tid = threadIdx.x;
    for (int i = tid; i < C * C / 4; i += 512) {
        ((float4*)wl)[i] = ((const float4*)Wl)[i];
        ((float4*)wr)[i] = ((const float4*)Wr)[i];
    }

    int node0 = blockIdx.x * 64;
    for (int i = tid; i < 64 * 16; i += 512) {
        int nl = i >> 4;
        int c4 = i & 15;
        int n = node0 + nl;
        int nc = n < NN ? n : NN - 1;
        float4 v = ((const float4*)xin)[(size_t)nc * 16 + c4];
        *(float4*)&xs[nl][c4 * 4] = v;
    }
    __syncthreads();

    int c4 = tid & 15;
    int np = tid >> 4;
    float4 b4 = ((const float4*)bias)[c4];
    float4 y0 = make_float4(0.f, 0.f, 0.f, 0.f);
    float4 y1 = make_float4(0.f, 0.f, 0.f, 0.f);
    float4 z0 = b4;
    float4 z1 = b4;
    #pragma unroll 16
    for (int k = 0; k < C; k++) {
        float xv0 = xs[np][k];
        float xv1 = xs[np + 32][k];
        float4 wlv = *(const float4*)&wl[k * C + c4 * 4];
        float4 wrv = *(const float4*)&wr[k * C + c4 * 4];
        y0.x += xv0 * wlv.x; y0.y += xv0 * wlv.y; y0.z += xv0 * wlv.z; y0.w += xv0 * wlv.w;
        z0.x += xv0 * wrv.x; z0.y += xv0 * wrv.y; z0.z += xv0 * wrv.z; z0.w += xv0 * wrv.w;
        y1.x += xv1 * wlv.x; y1.y += xv1 * wlv.y; y1.z += xv1 * wlv.z; y1.w += xv1 * wlv.w;
        z1.x += xv1 * wrv.x; z1.y += xv1 * wrv.y; z1.z += xv1 * wrv.z; z1.w += xv1 * wrv.w;
    }
    int n0 = node0 + np;
    int n1 = node0 + np + 32;
    if (n0 < NN) {
        ((float4*)y)[(size_t)n0 * 16 + c4] = y0;
        ((float4*)z)[(size_t)n0 * 16 + c4] = z0;
    }
    if (n1 < NN) {
        ((float4*)y)[(size_t)n1 * 16 + c4] = y1;
        ((float4*)z)[(size_t)n1 * 16 + c4] = z1;
    }
}

// ---------------- fused: gather layer l -> prelu -> LDS -> transform layer l+1 ----------------
__global__ __launch_bounds__(512) void fused_gt_kernel(
    const float4* __restrict__ y4, const float4* __restrict__ z4,
    const int* __restrict__ row_start, const int* __restrict__ deg_cnt,
    const float* __restrict__ deg_inv, const float* __restrict__ alpha,
    const int* __restrict__ csr_src,
    const float* __restrict__ Wl2, const float* __restrict__ Wr2,
    const float* __restrict__ bias2,
    float* __restrict__ yout, float* __restrict__ zout)
{
    __shared__ float wl[C * C];
    __shared__ float wr[C * C];
    __shared__ float xs[32][C + 4];
    __shared__ float bs2[C];

    int tid = threadIdx.x;
    for (int i = tid; i < C * C / 4; i += 512) {
        ((float4*)wl)[i] = ((const float4*)Wl2)[i];
        ((float4*)wr)[i] = ((const float4*)Wr2)[i];
    }
    if (tid < C) bs2[tid] = bias2[tid];

    int nl = tid >> 4;        // 0..31
    int ql = tid & 15;
    int n = blockIdx.x * 32 + nl;

    float4 o = make_float4(0.f, 0.f, 0.f, 0.f);
    if (n < NN) {
        int rs = row_start[n];
        int dpad = (deg_cnt[n] + 7) & ~7;
        float4 acc = gather_row(y4, csr_src + rs, dpad, ql);
        float di = deg_inv[n];
        float4 zz = z4[(size_t)n * 16 + ql];
        float4 a4 = ((const float4*)alpha)[ql];
        o.x = di * acc.x + zz.x;
        o.y = di * acc.y + zz.y;
        o.z = di * acc.z + zz.z;
        o.w = di * acc.w + zz.w;
        o.x = o.x >= 0.f ? o.x : a4.x * o.x;
        o.y = o.y >= 0.f ? o.y : a4.y * o.y;
        o.z = o.z >= 0.f ? o.z : a4.z * o.z;
        o.w = o.w >= 0.f ? o.w : a4.w * o.w;
    }
    *(float4*)&xs[nl][ql * 4] = o;
    __syncthreads();

    float4 b4 = *(const float4*)&bs2[ql * 4];
    float4 yv = make_float4(0.f, 0.f, 0.f, 0.f);
    float4 zv = b4;
    #pragma unroll 16
    for (int k = 0; k < C; k++) {
        float xv = xs[nl][k];
        float4 wlv = *(const float4*)&wl[k * C + ql * 4];
        float4 wrv = *(const float4*)&wr[k * C + ql * 4];
        yv.x += xv * wlv.x; yv.y += xv * wlv.y; yv.z += xv * wlv.z; yv.w += xv * wlv.w;
        zv.x += xv * wrv.x; zv.y += xv * wrv.y; zv.z += xv * wrv.z; zv.w += xv * wrv.w;
    }
    if (n < NN) {
        ((float4*)yout)[(size_t)n * 16 + ql] = yv;
        ((float4*)zout)[(size_t)n * 16 + ql] = zv;
    }
}

// ---------------- final gather (layer 3): writes d_out ----------------
__global__ __launch_bounds__(256) void gather_kernel(
    const float4* __restrict__ y4, const float4* __restrict__ z4,
    const int* __restrict__ row_start, const int* __restrict__ deg_cnt,
    const float* __restrict__ deg_inv, const float* __restrict__ alpha,
    const int* __restrict__ csr_src,
    float4* __restrict__ out4)
{
    int tid = threadIdx.x;
    int n = blockIdx.x * 16 + (tid >> 4);   // 3125*16 = 50000 exact
    int ql = tid & 15;

    int rs = row_start[n];
    int dpad = (deg_cnt[n] + 7) & ~7;
    float4 acc = gather_row(y4, csr_src + rs, dpad, ql);

    float di = deg_inv[n];
    float4 zz = z4[(size_t)n * 16 + ql];
    float4 a4 = ((const float4*)alpha)[ql];
    float4 o;
    o.x = di * acc.x + zz.x;
    o.y = di * acc.y + zz.y;
    o.z = di * acc.z + zz.z;
    o.w = di * acc.w + zz.w;
    o.x = o.x >= 0.f ? o.x : a4.x * o.x;
    o.y = o.y >= 0.f ? o.y : a4.y * o.y;
    o.z = o.z >= 0.f ? o.z : a4.z * o.z;
    o.w = o.w >= 0.f ? o.w : a4.w * o.w;
    out4[(size_t)n * 16 + ql] = o;
}

extern "C" void kernel_launch(void* const* d_in, const int* in_sizes, int n_in,
                              void* d_out, int out_size, void* d_ws, size_t ws_size,
                              hipStream_t stream) {
    const float* x     = (const float*)d_in[0];
    const int*   ei    = (const int*)d_in[1];
    const float* Wl    = (const float*)d_in[2];
    const float* Wr    = (const float*)d_in[3];
    const float* b     = (const float*)d_in[4];
    const float* alpha = (const float*)d_in[5];
    float* out = (float*)d_out;

    const int* src = ei;        // edge_index[0]
    const int* dst = ei + NE;   // edge_index[1]

    // workspace layout (y/z bufs sized NN+1 rows; row NN of y = dummy zero)
    char* wsp = (char*)d_ws;
    int*   deg_cnt   = (int*)wsp;                   wsp += (size_t)(NN + 16) * 4;
    float* deg_inv   = (float*)wsp;                 wsp += (size_t)NN * 4;
    int*   row_start = (int*)wsp;                   wsp += (size_t)NN * 4;
    int*   bsums     = (int*)wsp;                   wsp += 256 * 4;
    int*   rankb     = (int*)wsp;                   wsp += (size_t)NE * 4;
    int*   csr_src   = (int*)wsp;                   wsp += (size_t)CSR_CAP * 4;
    float* y0buf     = (float*)wsp;                 wsp += (size_t)(NN + 1) * C * 4;
    float* z0buf     = (float*)wsp;                 wsp += (size_t)(NN + 1) * C * 4;
    float* y1buf     = (float*)wsp;                 wsp += (size_t)(NN + 1) * C * 4;
    float* z1buf     = (float*)wsp;

    // ---- CSR build ----
    init_kernel<<<1024, 256, 0, stream>>>(deg_cnt, csr_src, y0buf, y1buf);
    hist_rank_kernel<<<(NE / 4 + 255) / 256, 256, 0, stream>>>(dst, deg_cnt, rankb);
    scan1_kernel<<<SCAN_NB, 256, 0, stream>>>(deg_cnt, row_start, bsums);
    scan23_kernel<<<SCAN_NB, 256, 0, stream>>>(row_start, bsums, deg_cnt, deg_inv);
    fill_kernel<<<(NE / 4 + 255) / 256, 256, 0, stream>>>(src, dst, rankb, row_start, csr_src);

    // ---- layer 0 transform ----
    transform_kernel<<<(NN + 63) / 64, 512, 0, stream>>>(
        x, Wl, Wr, b, y0buf, z0buf);

    // ---- fused (gather_l + transform_{l+1}) for l = 0,1,2; ping-pong ----
    const int fblocks = (NN + 31) / 32;
    float* ycur = y0buf; float* zcur = z0buf;
    float* ynxt = y1buf; float* znxt = z1buf;
    for (int l = 0; l < NL - 1; l++) {
        fused_gt_kernel<<<fblocks, 512, 0, stream>>>(
            (const float4*)ycur, (const float4*)zcur,
            row_start, deg_cnt, deg_inv, alpha + (size_t)l * C, csr_src,
            Wl + (size_t)(l + 1) * C * C, Wr + (size_t)(l + 1) * C * C,
            b + (size_t)(l + 1) * C,
            ynxt, znxt);
        float* ty = ycur; float* tz = zcur;
        ycur = ynxt; zcur = znxt;
        ynxt = ty;   znxt = tz;
    }

    // ---- final gather (layer 3) -> d_out ----
    gather_kernel<<<NN / 16, 256, 0, stream>>>(
        (const float4*)ycur, (const float4*)zcur, row_start, deg_cnt,
        deg_inv, alpha + (size_t)(NL - 1) * C, csr_src, (float4*)out);
}

// Round 10
// 195.418 us; speedup vs baseline: 1.1303x; 1.1303x over previous
//
#include <hip/hip_runtime.h>

#define NN 50000
#define NE 800000
#define C 64
#define NL 4
#define SCAN_NB 196        // ceil(50000/256)
#define TBLOCKS 782        // ceil(NN/64) transform blocks
#define HBLOCKS 391        // ceil(NE/(512*4)) hist blocks

// ---- bf16 helpers (RNE) ----
__device__ __forceinline__ unsigned short f2bf(float f) {
    unsigned u = __float_as_uint(f);
    u += 0x7fffu + ((u >> 16) & 1u);
    return (unsigned short)(u >> 16);
}
__device__ __forceinline__ float4 bf4_to_f4(uint2 p) {
    float4 r;
    r.x = __uint_as_float(p.x << 16);
    r.y = __uint_as_float(p.x & 0xffff0000u);
    r.z = __uint_as_float(p.y << 16);
    r.w = __uint_as_float(p.y & 0xffff0000u);
    return r;
}

// ---------------- init: zero deg_cnt ----------------
__global__ void init_kernel(int4* __restrict__ p) {
    int i = blockIdx.x * blockDim.x + threadIdx.x;
    if (i < (NN + 16) / 4) p[i] = make_int4(0, 0, 0, 0);
}

// ---------------- combined: layer-0 transform (blocks < TBLOCKS) || hist+rank ----------------
__global__ __launch_bounds__(512) void transform_hist_kernel(
    const float* __restrict__ xin,
    const float* __restrict__ Wl, const float* __restrict__ Wr,
    const float* __restrict__ bias,
    unsigned short* __restrict__ y, float* __restrict__ z,
    const int* __restrict__ dst, int* __restrict__ deg_cnt, int* __restrict__ rank)
{
    __shared__ float wl[C * C];
    __shared__ float wr[C * C];
    __shared__ float xs[64][C + 4];

    int tid = threadIdx.x;
    if (blockIdx.x >= TBLOCKS) {
        // ---- histogram + rank: 4 edges/thread ----
        int t = (blockIdx.x - TBLOCKS) * 512 + tid;
        int e0 = t * 4;
        if (e0 + 3 < NE) {
            int4 d4 = ((const int4*)dst)[t];
            int4 r4;
            r4.x = atomicAdd(&deg_cnt[d4.x], 1);
            r4.y = atomicAdd(&deg_cnt[d4.y], 1);
            r4.z = atomicAdd(&deg_cnt[d4.z], 1);
            r4.w = atomicAdd(&deg_cnt[d4.w], 1);
            ((int4*)rank)[t] = r4;
        } else if (e0 < NE) {
            for (int e = e0; e < NE; e++)
                rank[e] = atomicAdd(&deg_cnt[dst[e]], 1);
        }
        return;
    }

    // ---- transform: y = x@Wl (bf16), z = x@Wr + b (fp32) ----
    for (int i = tid; i < C * C / 4; i += 512) {
        ((float4*)wl)[i] = ((const float4*)Wl)[i];
        ((float4*)wr)[i] = ((const float4*)Wr)[i];
    }
    int node0 = blockIdx.x * 64;
    for (int i = tid; i < 64 * 16; i += 512) {
        int nl = i >> 4;
        int c4 = i & 15;
        int n = node0 + nl;
        int nc = n < NN ? n : NN - 1;
        float4 v = ((const float4*)xin)[(size_t)nc * 16 + c4];
        *(float4*)&xs[nl][c4 * 4] = v;
    }
    __syncthreads();

    int c4 = tid & 15;
    int np = tid >> 4;
    float4 b4 = ((const float4*)bias)[c4];
    float4 y0 = make_float4(0.f, 0.f, 0.f, 0.f);
    float4 y1 = make_float4(0.f, 0.f, 0.f, 0.f);
    float4 z0 = b4;
    float4 z1 = b4;
    #pragma unroll 16
    for (int k = 0; k < C; k++) {
        float xv0 = xs[np][k];
        float xv1 = xs[np + 32][k];
        float4 wlv = *(const float4*)&wl[k * C + c4 * 4];
        float4 wrv = *(const float4*)&wr[k * C + c4 * 4];
        y0.x += xv0 * wlv.x; y0.y += xv0 * wlv.y; y0.z += xv0 * wlv.z; y0.w += xv0 * wlv.w;
        z0.x += xv0 * wrv.x; z0.y += xv0 * wrv.y; z0.z += xv0 * wrv.z; z0.w += xv0 * wrv.w;
        y1.x += xv1 * wlv.x; y1.y += xv1 * wlv.y; y1.z += xv1 * wlv.z; y1.w += xv1 * wlv.w;
        z1.x += xv1 * wrv.x; z1.y += xv1 * wrv.y; z1.z += xv1 * wrv.z; z1.w += xv1 * wrv.w;
    }
    int n0 = node0 + np;
    int n1 = node0 + np + 32;
    if (n0 < NN) {
        ushort4 p = make_ushort4(f2bf(y0.x), f2bf(y0.y), f2bf(y0.z), f2bf(y0.w));
        *(ushort4*)&y[(size_t)n0 * C + c4 * 4] = p;
        ((float4*)z)[(size_t)n0 * 16 + c4] = z0;
    }
    if (n1 < NN) {
        ushort4 p = make_ushort4(f2bf(y1.x), f2bf(y1.y), f2bf(y1.z), f2bf(y1.w));
        *(ushort4*)&y[(size_t)n1 * C + c4 * 4] = p;
        ((float4*)z)[(size_t)n1 * 16 + c4] = z1;
    }
}

// ---------------- scan1 ----------------
__global__ __launch_bounds__(256) void scan1_kernel(const int* __restrict__ deg_cnt,
                                                    int* __restrict__ row_start,
                                                    int* __restrict__ bsums) {
    __shared__ int sdata[256];
    int tid = threadIdx.x;
    int i = blockIdx.x * 256 + tid;
    int v = (i < NN) ? deg_cnt[i] : 0;
    sdata[tid] = v;
    __syncthreads();
    for (int off = 1; off < 256; off <<= 1) {
        int t = (tid >= off) ? sdata[tid - off] : 0;
        __syncthreads();
        sdata[tid] += t;
        __syncthreads();
    }
    int incl = sdata[tid];
    if (i < NN) row_start[i] = incl - v;
    if (tid == 255) bsums[blockIdx.x] = incl;
}

// ---------------- scan23 ----------------
__global__ __launch_bounds__(256) void scan23_kernel(int* __restrict__ row_start,
                                                     const int* __restrict__ bsums,
                                                     const int* __restrict__ deg_cnt,
                                                     float* __restrict__ deg_inv) {
    __shared__ int sdata[256];
    int tid = threadIdx.x;
    int v = (tid < SCAN_NB) ? bsums[tid] : 0;
    sdata[tid] = v;
    __syncthreads();
    for (int off = 1; off < 256; off <<= 1) {
        int t = (tid >= off) ? sdata[tid - off] : 0;
        __syncthreads();
        sdata[tid] += t;
        __syncthreads();
    }
    int b = blockIdx.x;
    int offset = (b == 0) ? 0 : sdata[b - 1];
    int i = b * 256 + tid;
    if (i < NN) {
        row_start[i] += offset;
        deg_inv[i] = 1.0f / fmaxf((float)deg_cnt[i], 1.0f);
    }
}

// ---------------- CSR fill: no atomics, 4 edges/thread ----------------
__global__ void fill_kernel(const int* __restrict__ src, const int* __restrict__ dst,
                            const int* __restrict__ rank, const int* __restrict__ row_start,
                            int* __restrict__ csr_src) {
    int t = blockIdx.x * blockDim.x + threadIdx.x;
    int e0 = t * 4;
    if (e0 + 3 < NE) {
        int4 d4 = ((const int4*)dst)[t];
        int4 r4 = ((const int4*)rank)[t];
        int4 s4 = ((const int4*)src)[t];
        csr_src[row_start[d4.x] + r4.x] = s4.x;
        csr_src[row_start[d4.y] + r4.y] = s4.y;
        csr_src[row_start[d4.z] + r4.z] = s4.z;
        csr_src[row_start[d4.w] + r4.w] = s4.w;
    } else if (e0 < NE) {
        for (int e = e0; e < NE; e++)
            csr_src[row_start[dst[e]] + rank[e]] = src[e];
    }
}

// ---------------- gather core: bf16 rows, masked unroll-8 ----------------
// row = 64 bf16 = 128B = 16 uint2; lane ql loads uint2 (channels ql*4..ql*4+3)
__device__ __forceinline__ float4 gather_row(const uint2* __restrict__ yb,
                                             const int* __restrict__ cp, int d, int ql) {
    float4 acc = make_float4(0.f, 0.f, 0.f, 0.f);
    for (int t = 0; t < d; t += 8) {
        int lim = d - 1 - t;
        int j1 = min(1, lim), j2 = min(2, lim), j3 = min(3, lim);
        int j4 = min(4, lim), j5 = min(5, lim), j6 = min(6, lim), j7 = min(7, lim);
        float m1 = lim >= 1 ? 1.f : 0.f, m2 = lim >= 2 ? 1.f : 0.f;
        float m3 = lim >= 3 ? 1.f : 0.f, m4 = lim >= 4 ? 1.f : 0.f;
        float m5 = lim >= 5 ? 1.f : 0.f, m6 = lim >= 6 ? 1.f : 0.f;
        float m7 = lim >= 7 ? 1.f : 0.f;
        int s0 = cp[t];
        int s1 = cp[t + j1];
        int s2 = cp[t + j2];
        int s3 = cp[t + j3];
        int s4 = cp[t + j4];
        int s5 = cp[t + j5];
        int s6 = cp[t + j6];
        int s7 = cp[t + j7];
        uint2 p0 = yb[(size_t)s0 * 16 + ql];
        uint2 p1 = yb[(size_t)s1 * 16 + ql];
        uint2 p2 = yb[(size_t)s2 * 16 + ql];
        uint2 p3 = yb[(size_t)s3 * 16 + ql];
        uint2 p4 = yb[(size_t)s4 * 16 + ql];
        uint2 p5 = yb[(size_t)s5 * 16 + ql];
        uint2 p6 = yb[(size_t)s6 * 16 + ql];
        uint2 p7 = yb[(size_t)s7 * 16 + ql];
        float4 v0 = bf4_to_f4(p0);
        float4 v1 = bf4_to_f4(p1);
        float4 v2 = bf4_to_f4(p2);
        float4 v3 = bf4_to_f4(p3);
        float4 v4 = bf4_to_f4(p4);
        float4 v5 = bf4_to_f4(p5);
        float4 v6 = bf4_to_f4(p6);
        float4 v7 = bf4_to_f4(p7);
        acc.x += v0.x;      acc.y += v0.y;      acc.z += v0.z;      acc.w += v0.w;
        acc.x += v1.x * m1; acc.y += v1.y * m1; acc.z += v1.z * m1; acc.w += v1.w * m1;
        acc.x += v2.x * m2; acc.y += v2.y * m2; acc.z += v2.z * m2; acc.w += v2.w * m2;
        acc.x += v3.x * m3; acc.y += v3.y * m3; acc.z += v3.z * m3; acc.w += v3.w * m3;
        acc.x += v4.x * m4; acc.y += v4.y * m4; acc.z += v4.z * m4; acc.w += v4.w * m4;
        acc.x += v5.x * m5; acc.y += v5.y * m5; acc.z += v5.z * m5; acc.w += v5.w * m5;
        acc.x += v6.x * m6; acc.y += v6.y * m6; acc.z += v6.z * m6; acc.w += v6.w * m6;
        acc.x += v7.x * m7; acc.y += v7.y * m7; acc.z += v7.z * m7; acc.w += v7.w * m7;
    }
    return acc;
}

// ---------------- fused: gather layer l -> prelu -> LDS -> transform layer l+1 ----------------
__global__ __launch_bounds__(512) void fused_gt_kernel(
    const uint2* __restrict__ yb, const float4* __restrict__ z4,
    const int* __restrict__ row_start, const int* __restrict__ deg_cnt,
    const float* __restrict__ deg_inv, const float* __restrict__ alpha,
    const int* __restrict__ csr_src,
    const float* __restrict__ Wl2, const float* __restrict__ Wr2,
    const float* __restrict__ bias2,
    unsigned short* __restrict__ yout, float* __restrict__ zout)
{
    __shared__ float wl[C * C];
    __shared__ float wr[C * C];
    __shared__ float xs[32][C + 4];
    __shared__ float bs2[C];

    int tid = threadIdx.x;
    for (int i = tid; i < C * C / 4; i += 512) {
        ((float4*)wl)[i] = ((const float4*)Wl2)[i];
        ((float4*)wr)[i] = ((const float4*)Wr2)[i];
    }
    if (tid < C) bs2[tid] = bias2[tid];

    int nl = tid >> 4;        // 0..31
    int ql = tid & 15;
    int n = blockIdx.x * 32 + nl;

    float4 o = make_float4(0.f, 0.f, 0.f, 0.f);
    if (n < NN) {
        int rs = row_start[n];
        int d = deg_cnt[n];
        float4 acc = gather_row(yb, csr_src + rs, d, ql);
        float di = deg_inv[n];
        float4 zz = z4[(size_t)n * 16 + ql];
        float4 a4 = ((const float4*)alpha)[ql];
        o.x = di * acc.x + zz.x;
        o.y = di * acc.y + zz.y;
        o.z = di * acc.z + zz.z;
        o.w = di * acc.w + zz.w;
        o.x = o.x >= 0.f ? o.x : a4.x * o.x;
        o.y = o.y >= 0.f ? o.y : a4.y * o.y;
        o.z = o.z >= 0.f ? o.z : a4.z * o.z;
        o.w = o.w >= 0.f ? o.w : a4.w * o.w;
    }
    *(float4*)&xs[nl][ql * 4] = o;
    __syncthreads();

    float4 b4 = *(const float4*)&bs2[ql * 4];
    float4 yv = make_float4(0.f, 0.f, 0.f, 0.f);
    float4 zv = b4;
    #pragma unroll 16
    for (int k = 0; k < C; k++) {
        float xv = xs[nl][k];
        float4 wlv = *(const float4*)&wl[k * C + ql * 4];
        float4 wrv = *(const float4*)&wr[k * C + ql * 4];
        yv.x += xv * wlv.x; yv.y += xv * wlv.y; yv.z += xv * wlv.z; yv.w += xv * wlv.w;
        zv.x += xv * wrv.x; zv.y += xv * wrv.y; zv.z += xv * wrv.z; zv.w += xv * wrv.w;
    }
    if (n < NN) {
        ushort4 p = make_ushort4(f2bf(yv.x), f2bf(yv.y), f2bf(yv.z), f2bf(yv.w));
        *(ushort4*)&yout[(size_t)n * C + ql * 4] = p;
        ((float4*)zout)[(size_t)n * 16 + ql] = zv;
    }
}

// ---------------- final gather (layer 3): writes d_out fp32 ----------------
__global__ __launch_bounds__(256) void gather_kernel(
    const uint2* __restrict__ yb, const float4* __restrict__ z4,
    const int* __restrict__ row_start, const int* __restrict__ deg_cnt,
    const float* __restrict__ deg_inv, const float* __restrict__ alpha,
    const int* __restrict__ csr_src,
    float4* __restrict__ out4)
{
    int tid = threadIdx.x;
    int n = blockIdx.x * 16 + (tid >> 4);   // 3125*16 = 50000 exact
    int ql = tid & 15;

    int rs = row_start[n];
    int d = deg_cnt[n];
    float4 acc = gather_row(yb, csr_src + rs, d, ql);

    float di = deg_inv[n];
    float4 zz = z4[(size_t)n * 16 + ql];
    float4 a4 = ((const float4*)alpha)[ql];
    float4 o;
    o.x = di * acc.x + zz.x;
    o.y = di * acc.y + zz.y;
    o.z = di * acc.z + zz.z;
    o.w = di * acc.w + zz.w;
    o.x = o.x >= 0.f ? o.x : a4.x * o.x;
    o.y = o.y >= 0.f ? o.y : a4.y * o.y;
    o.z = o.z >= 0.f ? o.z : a4.z * o.z;
    o.w = o.w >= 0.f ? o.w : a4.w * o.w;
    out4[(size_t)n * 16 + ql] = o;
}

extern "C" void kernel_launch(void* const* d_in, const int* in_sizes, int n_in,
                              void* d_out, int out_size, void* d_ws, size_t ws_size,
                              hipStream_t stream) {
    const float* x     = (const float*)d_in[0];
    const int*   ei    = (const int*)d_in[1];
    const float* Wl    = (const float*)d_in[2];
    const float* Wr    = (const float*)d_in[3];
    const float* b     = (const float*)d_in[4];
    const float* alpha = (const float*)d_in[5];
    float* out = (float*)d_out;

    const int* src = ei;        // edge_index[0]
    const int* dst = ei + NE;   // edge_index[1]

    // workspace layout (all blocks 16B-aligned)
    char* wsp = (char*)d_ws;
    int*   deg_cnt   = (int*)wsp;                   wsp += (size_t)(NN + 16) * 4;
    float* deg_inv   = (float*)wsp;                 wsp += (size_t)NN * 4;
    int*   row_start = (int*)wsp;                   wsp += (size_t)NN * 4;
    int*   bsums     = (int*)wsp;                   wsp += 1024;
    int*   rankb     = (int*)wsp;                   wsp += (size_t)NE * 4;
    int*   csr_src   = (int*)wsp;                   wsp += (size_t)NE * 4;
    unsigned short* y0buf = (unsigned short*)wsp;   wsp += (size_t)NN * C * 2;
    unsigned short* y1buf = (unsigned short*)wsp;   wsp += (size_t)NN * C * 2;
    float* z0buf     = (float*)wsp;                 wsp += (size_t)NN * C * 4;
    float* z1buf     = (float*)wsp;

    // ---- CSR build + layer-0 transform (overlapped) ----
    init_kernel<<<49, 256, 0, stream>>>((int4*)deg_cnt);
    transform_hist_kernel<<<TBLOCKS + HBLOCKS, 512, 0, stream>>>(
        x, Wl, Wr, b, y0buf, z0buf, dst, deg_cnt, rankb);
    scan1_kernel<<<SCAN_NB, 256, 0, stream>>>(deg_cnt, row_start, bsums);
    scan23_kernel<<<SCAN_NB, 256, 0, stream>>>(row_start, bsums, deg_cnt, deg_inv);
    fill_kernel<<<(NE / 4 + 255) / 256, 256, 0, stream>>>(src, dst, rankb, row_start, csr_src);

    // ---- fused (gather_l + transform_{l+1}) for l = 0,1,2; ping-pong ----
    const int fblocks = (NN + 31) / 32;
    unsigned short* ycur = y0buf; float* zcur = z0buf;
    unsigned short* ynxt = y1buf; float* znxt = z1buf;
    for (int l = 0; l < NL - 1; l++) {
        fused_gt_kernel<<<fblocks, 512, 0, stream>>>(
            (const uint2*)ycur, (const float4*)zcur,
            row_start, deg_cnt, deg_inv, alpha + (size_t)l * C, csr_src,
            Wl + (size_t)(l + 1) * C * C, Wr + (size_t)(l + 1) * C * C,
            b + (size_t)(l + 1) * C,
            ynxt, znxt);
        unsigned short* ty = ycur; float* tz = zcur;
        ycur = ynxt; zcur = znxt;
        ynxt = ty;   znxt = tz;
    }

    // ---- final gather (layer 3) -> d_out ----
    gather_kernel<<<NN / 16, 256, 0, stream>>>(
        (const uint2*)ycur, (const float4*)zcur, row_start, deg_cnt,
        deg_inv, alpha + (size_t)(NL - 1) * C, csr_src, (float4*)out);
}

// Round 11
// 193.327 us; speedup vs baseline: 1.1425x; 1.0108x over previous
//
#include <hip/hip_runtime.h>

#define NN 50000
#define NE 800000
#define C 64
#define NL 4
#define SCAN_NB 196        // ceil(50000/256)

// ---- bf16 helpers (RNE) ----
__device__ __forceinline__ unsigned short f2bf(float f) {
    unsigned u = __float_as_uint(f);
    u += 0x7fffu + ((u >> 16) & 1u);
    return (unsigned short)(u >> 16);
}
__device__ __forceinline__ float4 bf4_to_f4(uint2 p) {
    float4 r;
    r.x = __uint_as_float(p.x << 16);
    r.y = __uint_as_float(p.x & 0xffff0000u);
    r.z = __uint_as_float(p.y << 16);
    r.w = __uint_as_float(p.y & 0xffff0000u);
    return r;
}

// ---------------- init: zero deg_cnt ----------------
__global__ void init_kernel(int4* __restrict__ p) {
    int i = blockIdx.x * blockDim.x + threadIdx.x;
    if (i < (NN + 16) / 4) p[i] = make_int4(0, 0, 0, 0);
}

// ---------------- degree histogram + per-edge rank: 1 edge/thread, no LDS ----------------
__global__ void hist_rank_kernel(const int* __restrict__ dst, int* __restrict__ deg_cnt,
                                 int* __restrict__ rank) {
    int e = blockIdx.x * blockDim.x + threadIdx.x;
    if (e < NE) rank[e] = atomicAdd(&deg_cnt[dst[e]], 1);
}

// ---------------- scan1 ----------------
__global__ __launch_bounds__(256) void scan1_kernel(const int* __restrict__ deg_cnt,
                                                    int* __restrict__ row_start,
                                                    int* __restrict__ bsums) {
    __shared__ int sdata[256];
    int tid = threadIdx.x;
    int i = blockIdx.x * 256 + tid;
    int v = (i < NN) ? deg_cnt[i] : 0;
    sdata[tid] = v;
    __syncthreads();
    for (int off = 1; off < 256; off <<= 1) {
        int t = (tid >= off) ? sdata[tid - off] : 0;
        __syncthreads();
        sdata[tid] += t;
        __syncthreads();
    }
    int incl = sdata[tid];
    if (i < NN) row_start[i] = incl - v;
    if (tid == 255) bsums[blockIdx.x] = incl;
}

// ---------------- scan23 ----------------
__global__ __launch_bounds__(256) void scan23_kernel(int* __restrict__ row_start,
                                                     const int* __restrict__ bsums,
                                                     const int* __restrict__ deg_cnt,
                                                     float* __restrict__ deg_inv) {
    __shared__ int sdata[256];
    int tid = threadIdx.x;
    int v = (tid < SCAN_NB) ? bsums[tid] : 0;
    sdata[tid] = v;
    __syncthreads();
    for (int off = 1; off < 256; off <<= 1) {
        int t = (tid >= off) ? sdata[tid - off] : 0;
        __syncthreads();
        sdata[tid] += t;
        __syncthreads();
    }
    int b = blockIdx.x;
    int offset = (b == 0) ? 0 : sdata[b - 1];
    int i = b * 256 + tid;
    if (i < NN) {
        row_start[i] += offset;
        deg_inv[i] = 1.0f / fmaxf((float)deg_cnt[i], 1.0f);
    }
}

// ---------------- CSR fill: no atomics, 4 edges/thread ----------------
__global__ void fill_kernel(const int* __restrict__ src, const int* __restrict__ dst,
                            const int* __restrict__ rank, const int* __restrict__ row_start,
                            int* __restrict__ csr_src) {
    int t = blockIdx.x * blockDim.x + threadIdx.x;
    int e0 = t * 4;
    if (e0 + 3 < NE) {
        int4 d4 = ((const int4*)dst)[t];
        int4 r4 = ((const int4*)rank)[t];
        int4 s4 = ((const int4*)src)[t];
        csr_src[row_start[d4.x] + r4.x] = s4.x;
        csr_src[row_start[d4.y] + r4.y] = s4.y;
        csr_src[row_start[d4.z] + r4.z] = s4.z;
        csr_src[row_start[d4.w] + r4.w] = s4.w;
    } else if (e0 < NE) {
        for (int e = e0; e < NE; e++)
            csr_src[row_start[dst[e]] + rank[e]] = src[e];
    }
}

// ---------------- layer-0 transform: y = x@Wl (bf16), z = x@Wr + b (fp32) ----------------
__global__ __launch_bounds__(512) void transform_kernel(
    const float* __restrict__ xin,
    const float* __restrict__ Wl, const float* __restrict__ Wr,
    const float* __restrict__ bias,
    unsigned short* __restrict__ y, float* __restrict__ z)
{
    __shared__ float wl[C * C];
    __shared__ float wr[C * C];
    __shared__ float xs[64][C + 4];

    int tid = threadIdx.x;
    for (int i = tid; i < C * C / 4; i += 512) {
        ((float4*)wl)[i] = ((const float4*)Wl)[i];
        ((float4*)wr)[i] = ((const float4*)Wr)[i];
    }
    int node0 = blockIdx.x * 64;
    for (int i = tid; i < 64 * 16; i += 512) {
        int nl = i >> 4;
        int c4 = i & 15;
        int n = node0 + nl;
        int nc = n < NN ? n : NN - 1;
        float4 v = ((const float4*)xin)[(size_t)nc * 16 + c4];
        *(float4*)&xs[nl][c4 * 4] = v;
    }
    __syncthreads();

    int c4 = tid & 15;
    int np = tid >> 4;
    float4 b4 = ((const float4*)bias)[c4];
    float4 y0 = make_float4(0.f, 0.f, 0.f, 0.f);
    float4 y1 = make_float4(0.f, 0.f, 0.f, 0.f);
    float4 z0 = b4;
    float4 z1 = b4;
    #pragma unroll 16
    for (int k = 0; k < C; k++) {
        float xv0 = xs[np][k];
        float xv1 = xs[np + 32][k];
        float4 wlv = *(const float4*)&wl[k * C + c4 * 4];
        float4 wrv = *(const float4*)&wr[k * C + c4 * 4];
        y0.x += xv0 * wlv.x; y0.y += xv0 * wlv.y; y0.z += xv0 * wlv.z; y0.w += xv0 * wlv.w;
        z0.x += xv0 * wrv.x; z0.y += xv0 * wrv.y; z0.z += xv0 * wrv.z; z0.w += xv0 * wrv.w;
        y1.x += xv1 * wlv.x; y1.y += xv1 * wlv.y; y1.z += xv1 * wlv.z; y1.w += xv1 * wlv.w;
        z1.x += xv1 * wrv.x; z1.y += xv1 * wrv.y; z1.z += xv1 * wrv.z; z1.w += xv1 * wrv.w;
    }
    int n0 = node0 + np;
    int n1 = node0 + np + 32;
    if (n0 < NN) {
        ushort4 p = make_ushort4(f2bf(y0.x), f2bf(y0.y), f2bf(y0.z), f2bf(y0.w));
        *(ushort4*)&y[(size_t)n0 * C + c4 * 4] = p;
        ((float4*)z)[(size_t)n0 * 16 + c4] = z0;
    }
    if (n1 < NN) {
        ushort4 p = make_ushort4(f2bf(y1.x), f2bf(y1.y), f2bf(y1.z), f2bf(y1.w));
        *(ushort4*)&y[(size_t)n1 * C + c4 * 4] = p;
        ((float4*)z)[(size_t)n1 * 16 + c4] = z1;
    }
}

// ---------------- gather core: bf16 rows, masked unroll-8 ----------------
__device__ __forceinline__ float4 gather_row(const uint2* __restrict__ yb,
                                             const int* __restrict__ cp, int d, int ql) {
    float4 acc = make_float4(0.f, 0.f, 0.f, 0.f);
    for (int t = 0; t < d; t += 8) {
        int lim = d - 1 - t;
        int j1 = min(1, lim), j2 = min(2, lim), j3 = min(3, lim);
        int j4 = min(4, lim), j5 = min(5, lim), j6 = min(6, lim), j7 = min(7, lim);
        float m1 = lim >= 1 ? 1.f : 0.f, m2 = lim >= 2 ? 1.f : 0.f;
        float m3 = lim >= 3 ? 1.f : 0.f, m4 = lim >= 4 ? 1.f : 0.f;
        float m5 = lim >= 5 ? 1.f : 0.f, m6 = lim >= 6 ? 1.f : 0.f;
        float m7 = lim >= 7 ? 1.f : 0.f;
        int s0 = cp[t];
        int s1 = cp[t + j1];
        int s2 = cp[t + j2];
        int s3 = cp[t + j3];
        int s4 = cp[t + j4];
        int s5 = cp[t + j5];
        int s6 = cp[t + j6];
        int s7 = cp[t + j7];
        uint2 p0 = yb[(size_t)s0 * 16 + ql];
        uint2 p1 = yb[(size_t)s1 * 16 + ql];
        uint2 p2 = yb[(size_t)s2 * 16 + ql];
        uint2 p3 = yb[(size_t)s3 * 16 + ql];
        uint2 p4 = yb[(size_t)s4 * 16 + ql];
        uint2 p5 = yb[(size_t)s5 * 16 + ql];
        uint2 p6 = yb[(size_t)s6 * 16 + ql];
        uint2 p7 = yb[(size_t)s7 * 16 + ql];
        float4 v0 = bf4_to_f4(p0);
        float4 v1 = bf4_to_f4(p1);
        float4 v2 = bf4_to_f4(p2);
        float4 v3 = bf4_to_f4(p3);
        float4 v4 = bf4_to_f4(p4);
        float4 v5 = bf4_to_f4(p5);
        float4 v6 = bf4_to_f4(p6);
        float4 v7 = bf4_to_f4(p7);
        acc.x += v0.x;      acc.y += v0.y;      acc.z += v0.z;      acc.w += v0.w;
        acc.x += v1.x * m1; acc.y += v1.y * m1; acc.z += v1.z * m1; acc.w += v1.w * m1;
        acc.x += v2.x * m2; acc.y += v2.y * m2; acc.z += v2.z * m2; acc.w += v2.w * m2;
        acc.x += v3.x * m3; acc.y += v3.y * m3; acc.z += v3.z * m3; acc.w += v3.w * m3;
        acc.x += v4.x * m4; acc.y += v4.y * m4; acc.z += v4.z * m4; acc.w += v4.w * m4;
        acc.x += v5.x * m5; acc.y += v5.y * m5; acc.z += v5.z * m5; acc.w += v5.w * m5;
        acc.x += v6.x * m6; acc.y += v6.y * m6; acc.z += v6.z * m6; acc.w += v6.w * m6;
        acc.x += v7.x * m7; acc.y += v7.y * m7; acc.z += v7.z * m7; acc.w += v7.w * m7;
    }
    return acc;
}

// ---------------- fused: gather layer l -> prelu -> LDS -> transform layer l+1 ----------------
__global__ __launch_bounds__(512) void fused_gt_kernel(
    const uint2* __restrict__ yb, const float4* __restrict__ z4,
    const int* __restrict__ row_start, const int* __restrict__ deg_cnt,
    const float* __restrict__ deg_inv, const float* __restrict__ alpha,
    const int* __restrict__ csr_src,
    const float* __restrict__ Wl2, const float* __restrict__ Wr2,
    const float* __restrict__ bias2,
    unsigned short* __restrict__ yout, float* __restrict__ zout)
{
    __shared__ float wl[C * C];
    __shared__ float wr[C * C];
    __shared__ float xs[32][C + 4];
    __shared__ float bs2[C];

    int tid = threadIdx.x;
    for (int i = tid; i < C * C / 4; i += 512) {
        ((float4*)wl)[i] = ((const float4*)Wl2)[i];
        ((float4*)wr)[i] = ((const float4*)Wr2)[i];
    }
    if (tid < C) bs2[tid] = bias2[tid];

    int nl = tid >> 4;        // 0..31
    int ql = tid & 15;
    int n = blockIdx.x * 32 + nl;

    float4 o = make_float4(0.f, 0.f, 0.f, 0.f);
    if (n < NN) {
        int rs = row_start[n];
        int d = deg_cnt[n];
        float4 acc = gather_row(yb, csr_src + rs, d, ql);
        float di = deg_inv[n];
        float4 zz = z4[(size_t)n * 16 + ql];
        float4 a4 = ((const float4*)alpha)[ql];
        o.x = di * acc.x + zz.x;
        o.y = di * acc.y + zz.y;
        o.z = di * acc.z + zz.z;
        o.w = di * acc.w + zz.w;
        o.x = o.x >= 0.f ? o.x : a4.x * o.x;
        o.y = o.y >= 0.f ? o.y : a4.y * o.y;
        o.z = o.z >= 0.f ? o.z : a4.z * o.z;
        o.w = o.w >= 0.f ? o.w : a4.w * o.w;
    }
    *(float4*)&xs[nl][ql * 4] = o;
    __syncthreads();

    float4 b4 = *(const float4*)&bs2[ql * 4];
    float4 yv = make_float4(0.f, 0.f, 0.f, 0.f);
    float4 zv = b4;
    #pragma unroll 16
    for (int k = 0; k < C; k++) {
        float xv = xs[nl][k];
        float4 wlv = *(const float4*)&wl[k * C + ql * 4];
        float4 wrv = *(const float4*)&wr[k * C + ql * 4];
        yv.x += xv * wlv.x; yv.y += xv * wlv.y; yv.z += xv * wlv.z; yv.w += xv * wlv.w;
        zv.x += xv * wrv.x; zv.y += xv * wrv.y; zv.z += xv * wrv.z; zv.w += xv * wrv.w;
    }
    if (n < NN) {
        ushort4 p = make_ushort4(f2bf(yv.x), f2bf(yv.y), f2bf(yv.z), f2bf(yv.w));
        *(ushort4*)&yout[(size_t)n * C + ql * 4] = p;
        ((float4*)zout)[(size_t)n * 16 + ql] = zv;
    }
}

// ---------------- final gather (layer 3): writes d_out fp32 ----------------
__global__ __launch_bounds__(256) void gather_kernel(
    const uint2* __restrict__ yb, const float4* __restrict__ z4,
    const int* __restrict__ row_start, const int* __restrict__ deg_cnt,
    const float* __restrict__ deg_inv, const float* __restrict__ alpha,
    const int* __restrict__ csr_src,
    float4* __restrict__ out4)
{
    int tid = threadIdx.x;
    int n = blockIdx.x * 16 + (tid >> 4);   // 3125*16 = 50000 exact
    int ql = tid & 15;

    int rs = row_start[n];
    int d = deg_cnt[n];
    float4 acc = gather_row(yb, csr_src + rs, d, ql);

    float di = deg_inv[n];
    float4 zz = z4[(size_t)n * 16 + ql];
    float4 a4 = ((const float4*)alpha)[ql];
    float4 o;
    o.x = di * acc.x + zz.x;
    o.y = di * acc.y + zz.y;
    o.z = di * acc.z + zz.z;
    o.w = di * acc.w + zz.w;
    o.x = o.x >= 0.f ? o.x : a4.x * o.x;
    o.y = o.y >= 0.f ? o.y : a4.y * o.y;
    o.z = o.z >= 0.f ? o.z : a4.z * o.z;
    o.w = o.w >= 0.f ? o.w : a4.w * o.w;
    out4[(size_t)n * 16 + ql] = o;
}

extern "C" void kernel_launch(void* const* d_in, const int* in_sizes, int n_in,
                              void* d_out, int out_size, void* d_ws, size_t ws_size,
                              hipStream_t stream) {
    const float* x     = (const float*)d_in[0];
    const int*   ei    = (const int*)d_in[1];
    const float* Wl    = (const float*)d_in[2];
    const float* Wr    = (const float*)d_in[3];
    const float* b     = (const float*)d_in[4];
    const float* alpha = (const float*)d_in[5];
    float* out = (float*)d_out;

    const int* src = ei;        // edge_index[0]
    const int* dst = ei + NE;   // edge_index[1]

    // workspace layout (all blocks 16B-aligned)
    char* wsp = (char*)d_ws;
    int*   deg_cnt   = (int*)wsp;                   wsp += (size_t)(NN + 16) * 4;
    float* deg_inv   = (float*)wsp;                 wsp += (size_t)NN * 4;
    int*   row_start = (int*)wsp;                   wsp += (size_t)NN * 4;
    int*   bsums     = (int*)wsp;                   wsp += 1024;
    int*   rankb     = (int*)wsp;                   wsp += (size_t)NE * 4;
    int*   csr_src   = (int*)wsp;                   wsp += (size_t)NE * 4;
    unsigned short* y0buf = (unsigned short*)wsp;   wsp += (size_t)NN * C * 2;
    unsigned short* y1buf = (unsigned short*)wsp;   wsp += (size_t)NN * C * 2;
    float* z0buf     = (float*)wsp;                 wsp += (size_t)NN * C * 4;
    float* z1buf     = (float*)wsp;

    // ---- CSR build ----
    init_kernel<<<49, 256, 0, stream>>>((int4*)deg_cnt);
    hist_rank_kernel<<<(NE + 255) / 256, 256, 0, stream>>>(dst, deg_cnt, rankb);
    scan1_kernel<<<SCAN_NB, 256, 0, stream>>>(deg_cnt, row_start, bsums);
    scan23_kernel<<<SCAN_NB, 256, 0, stream>>>(row_start, bsums, deg_cnt, deg_inv);
    fill_kernel<<<(NE / 4 + 255) / 256, 256, 0, stream>>>(src, dst, rankb, row_start, csr_src);

    // ---- layer-0 transform ----
    transform_kernel<<<(NN + 63) / 64, 512, 0, stream>>>(x, Wl, Wr, b, y0buf, z0buf);

    // ---- fused (gather_l + transform_{l+1}) for l = 0,1,2; ping-pong ----
    const int fblocks = (NN + 31) / 32;
    unsigned short* ycur = y0buf; float* zcur = z0buf;
    unsigned short* ynxt = y1buf; float* znxt = z1buf;
    for (int l = 0; l < NL - 1; l++) {
        fused_gt_kernel<<<fblocks, 512, 0, stream>>>(
            (const uint2*)ycur, (const float4*)zcur,
            row_start, deg_cnt, deg_inv, alpha + (size_t)l * C, csr_src,
            Wl + (size_t)(l + 1) * C * C, Wr + (size_t)(l + 1) * C * C,
            b + (size_t)(l + 1) * C,
            ynxt, znxt);
        unsigned short* ty = ycur; float* tz = zcur;
        ycur = ynxt; zcur = znxt;
        ynxt = ty;   znxt = tz;
    }

    // ---- final gather (layer 3) -> d_out ----
    gather_kernel<<<NN / 16, 256, 0, stream>>>(
        (const uint2*)ycur, (const float4*)zcur, row_start, deg_cnt,
        deg_inv, alpha + (size_t)(NL - 1) * C, csr_src, (float4*)out);
}